// Round 2
// baseline (254.318 us; speedup 1.0000x reference)
//
#include <hip/hip_runtime.h>
#include <math.h>

#define UNITS 80
#define LATENT 128
#define IN_DIM 256
#define BATCH 8192
#define SEQ 256
#define G 320           // 4*UNITS
#define H2 160          // 2*UNITS

#define TPB 640         // 10 waves; 640 % 20 == 0 (yc float4 period)
#define RPB 4           // batch rows per block
#define NBLK (BATCH / RPB)   // 2048 blocks

__device__ __forceinline__ float sigf(float v) {
    return 1.0f / (1.0f + __expf(-v));
}

// ---------------------------------------------------------------------------
// Kernel 1: yc = decode_step(ones(128)). Input all-ones => z = colsum(K) + b.
// 640 threads: fw columns on t<320, bw columns on t>=320 (parallel halves).
// ---------------------------------------------------------------------------
__global__ __launch_bounds__(640)
void yc_kernel(const float* __restrict__ Kf, const float* __restrict__ bf,
               const float* __restrict__ Kb, const float* __restrict__ bb,
               const float* __restrict__ K1, const float* __restrict__ b1,
               float* __restrict__ yc) {
    __shared__ float z[2 * G];
    __shared__ float h[H2];
    const int t = threadIdx.x;   // 0..639

    {
        const float* K   = (t < G) ? Kf : Kb;
        const float* bia = (t < G) ? bf : bb;
        const int c = (t < G) ? t : t - G;
        float acc = bia[c];
#pragma unroll 8
        for (int l = 0; l < LATENT; ++l) acc += K[l * G + c];
        z[t] = acc;
    }
    __syncthreads();
    if (t < UNITS) {
        h[t] = sigf(z[240 + t]) * sigf(z[t]) * fmaxf(z[160 + t], 0.f);
    } else if (t >= G && t < G + UNITS) {
        const int u = t - G;
        h[UNITS + u] = sigf(z[G + 240 + u]) * sigf(z[G + u]) * fmaxf(z[G + 160 + u], 0.f);
    }
    __syncthreads();
    if (t < G) {
        float acc = b1[t];
#pragma unroll 8
        for (int l = 0; l < H2; ++l) acc = fmaf(h[l], K1[l * G + t], acc);
        z[t] = acc;
    }
    __syncthreads();
    if (t < UNITS) yc[t] = sigf(z[240 + t]) * sigf(z[t]) * fmaxf(z[160 + t], 0.f);
}

// ---------------------------------------------------------------------------
// Kernel 2: every block owns RPB=4 contiguous batch rows.
//   phase A: stream-broadcast yc into the rows' s>=1 region (pure float4 stores,
//            contiguous per block, zero per-iteration arithmetic beyond +stride)
//   phase B: compute y0 for the 4 rows and write the s=0 slices (~1 us, hidden)
// ---------------------------------------------------------------------------
__global__ __launch_bounds__(TPB)
void main_kernel(const float* __restrict__ x,
                 const float* __restrict__ Wl, const float* __restrict__ bl,
                 const float* __restrict__ Kf, const float* __restrict__ bf,
                 const float* __restrict__ Kb, const float* __restrict__ bb,
                 const float* __restrict__ K1, const float* __restrict__ b1,
                 const float* __restrict__ yc,
                 float* __restrict__ out) {
    __shared__ float xs[RPB * IN_DIM];      // 4 KB
    __shared__ float lat_s[RPB * LATENT];   // 2 KB
    __shared__ float h_s[RPB * H2];         // 2.5 KB
    __shared__ float4 yc4s[UNITS / 4];      // 320 B

    const int t = threadIdx.x;
    const int R0 = blockIdx.x * RPB;

    if (t < UNITS / 4) yc4s[t] = ((const float4*)yc)[t];
    // stage x tile (4 rows x 256 = 256 float4)
    {
        const float4* xg = (const float4*)(x + (size_t)R0 * IN_DIM);
        float4* xs4 = (float4*)xs;
        if (t < RPB * IN_DIM / 4) xs4[t] = xg[t];
    }
    __syncthreads();

    // ---------------- phase A: broadcast writes, s = 1..255 ----------------
    {
        const float4 yv = yc4s[t % (UNITS / 4)];    // constant per thread
        float4* out4 = (float4*)out;
        const int per_row = (SEQ - 1) * UNITS / 4;  // 5100
#pragma unroll
        for (int r = 0; r < RPB; ++r) {
            float4* rowp = out4 + (size_t)(R0 + r) * (SEQ * UNITS / 4) + (UNITS / 4);
#pragma unroll
            for (int k = 0; k < 8; ++k) {
                const int j = t + k * TPB;
                if (j < per_row) rowp[j] = yv;
            }
        }
    }

    // ---------------- phase B: y0 for rows R0..R0+3 ----------------
    // lat = x @ W_lat + b_lat : 512 outputs (4 rows x 128 cols)
    if (t < 512) {
        const int row = t >> 7, col = t & 127;
        float acc = bl[col];
        const float* xr = xs + row * IN_DIM;
#pragma unroll 8
        for (int l = 0; l < IN_DIM; ++l) acc = fmaf(xr[l], Wl[l * LATENT + col], acc);
        lat_s[row * LATENT + col] = acc;
    }
    __syncthreads();

    // fw gates on t<320, bw gates on t>=320 (f gate dead: c0=0; relu(c)=c as c>=0)
    {
        const int half = t / G;            // 0 = fw, 1 = bw (wave-uniform: 320 = 5 waves)
        const int tt = t - half * G;       // 0..319
        const int row = tt / UNITS;        // 0..3
        const int u = tt - row * UNITS;    // 0..79
        const float* K   = half ? Kb : Kf;
        const float* bia = half ? bb : bf;
        float ai = 0.f, ac = 0.f, ao = 0.f;
        const float* lr = lat_s + row * LATENT;
#pragma unroll 4
        for (int k = 0; k < LATENT; ++k) {
            const float lv = lr[k];
            ai = fmaf(lv, K[k * G + u], ai);
            ac = fmaf(lv, K[k * G + 160 + u], ac);
            ao = fmaf(lv, K[k * G + 240 + u], ao);
        }
        h_s[row * H2 + half * UNITS + u] =
            sigf(ao + bia[240 + u]) * sigf(ai + bia[u]) * fmaxf(ac + bia[160 + u], 0.f);
    }
    __syncthreads();

    // output LSTM: y0 = gates(h @ K_1 + b_1), write s=0 slice
    if (t < G) {
        const int row = t / UNITS;         // 0..3
        const int u = t - row * UNITS;     // 0..79
        float ai = 0.f, ac = 0.f, ao = 0.f;
        const float* hr = h_s + row * H2;
#pragma unroll 4
        for (int k = 0; k < H2; ++k) {
            const float hv = hr[k];
            ai = fmaf(hv, K1[k * G + u], ai);
            ac = fmaf(hv, K1[k * G + 160 + u], ac);
            ao = fmaf(hv, K1[k * G + 240 + u], ao);
        }
        const float y = sigf(ao + b1[240 + u]) * sigf(ai + b1[u]) * fmaxf(ac + b1[160 + u], 0.f);
        out[(size_t)(R0 + row) * SEQ * UNITS + u] = y;
    }
}

extern "C" void kernel_launch(void* const* d_in, const int* in_sizes, int n_in,
                              void* d_out, int out_size, void* d_ws, size_t ws_size,
                              hipStream_t stream) {
    const float* x   = (const float*)d_in[0];
    // d_in[1] = size (scalar, fixed 256)
    const float* Wl  = (const float*)d_in[2];
    const float* bl  = (const float*)d_in[3];
    const float* Kf  = (const float*)d_in[4];
    const float* bf  = (const float*)d_in[5];
    const float* Kb  = (const float*)d_in[6];
    const float* bb  = (const float*)d_in[7];
    const float* K1  = (const float*)d_in[8];
    const float* b1  = (const float*)d_in[9];
    float* out = (float*)d_out;
    float* yc  = (float*)d_ws;   // 80 floats

    yc_kernel<<<1, 640, 0, stream>>>(Kf, bf, Kb, bb, K1, b1, yc);
    main_kernel<<<NBLK, TPB, 0, stream>>>(x, Wl, bl, Kf, bf, Kb, bb, K1, b1, yc, out);
}

// Round 4
// 201.501 us; speedup vs baseline: 1.2621x; 1.2621x over previous
//
#include <hip/hip_runtime.h>
#include <math.h>

#define UNITS 80
#define LATENT 128
#define IN_DIM 256
#define BATCH 8192
#define SEQ 256
#define G 320           // 4*UNITS
#define H2 160          // 2*UNITS

#define TPB 640         // 10 waves; 640 % 20 == 0 (yc float4 period)
#define RPB 4           // batch rows per block
#define NBLK (BATCH / RPB)   // 2048 blocks

typedef float f4 __attribute__((ext_vector_type(4)));   // nt-store-compatible

__device__ __forceinline__ float sigf(float v) {
    return 1.0f / (1.0f + __expf(-v));
}

// ---------------------------------------------------------------------------
// Kernel 1: yc = decode_step(ones(128)). Input all-ones => z = colsum(K) + b.
// 640 threads: fw columns on t<320, bw columns on t>=320 (parallel halves).
// ---------------------------------------------------------------------------
__global__ __launch_bounds__(640)
void yc_kernel(const float* __restrict__ Kf, const float* __restrict__ bf,
               const float* __restrict__ Kb, const float* __restrict__ bb,
               const float* __restrict__ K1, const float* __restrict__ b1,
               float* __restrict__ yc) {
    __shared__ float z[2 * G];
    __shared__ float h[H2];
    const int t = threadIdx.x;   // 0..639

    {
        const float* K   = (t < G) ? Kf : Kb;
        const float* bia = (t < G) ? bf : bb;
        const int c = (t < G) ? t : t - G;
        float acc = bia[c];
#pragma unroll 8
        for (int l = 0; l < LATENT; ++l) acc += K[l * G + c];
        z[t] = acc;
    }
    __syncthreads();
    if (t < UNITS) {
        h[t] = sigf(z[240 + t]) * sigf(z[t]) * fmaxf(z[160 + t], 0.f);
    } else if (t >= G && t < G + UNITS) {
        const int u = t - G;
        h[UNITS + u] = sigf(z[G + 240 + u]) * sigf(z[G + u]) * fmaxf(z[G + 160 + u], 0.f);
    }
    __syncthreads();
    if (t < G) {
        float acc = b1[t];
#pragma unroll 8
        for (int l = 0; l < H2; ++l) acc = fmaf(h[l], K1[l * G + t], acc);
        z[t] = acc;
    }
    __syncthreads();
    if (t < UNITS) yc[t] = sigf(z[240 + t]) * sigf(z[t]) * fmaxf(z[160 + t], 0.f);
}

// ---------------------------------------------------------------------------
// Kernel 2: every block owns RPB=4 contiguous batch rows.
//   phase A: stream-broadcast yc into the rows' s>=1 region via NON-TEMPORAL
//            float4 stores (bypass L2/L3 allocation -> no RFO read traffic)
//   phase B: compute y0 for the 4 rows and write the s=0 slices
// ---------------------------------------------------------------------------
__global__ __launch_bounds__(TPB)
void main_kernel(const float* __restrict__ x,
                 const float* __restrict__ Wl, const float* __restrict__ bl,
                 const float* __restrict__ Kf, const float* __restrict__ bf,
                 const float* __restrict__ Kb, const float* __restrict__ bb,
                 const float* __restrict__ K1, const float* __restrict__ b1,
                 const float* __restrict__ yc,
                 float* __restrict__ out) {
    __shared__ float xs[RPB * IN_DIM];      // 4 KB
    __shared__ float lat_s[RPB * LATENT];   // 2 KB
    __shared__ float h_s[RPB * H2];         // 2.5 KB
    __shared__ f4 yc4s[UNITS / 4];          // 320 B

    const int t = threadIdx.x;
    const int R0 = blockIdx.x * RPB;

    if (t < UNITS / 4) yc4s[t] = ((const f4*)yc)[t];
    // stage x tile (4 rows x 256 = 256 float4)
    {
        const f4* xg = (const f4*)(x + (size_t)R0 * IN_DIM);
        f4* xs4 = (f4*)xs;
        if (t < RPB * IN_DIM / 4) xs4[t] = xg[t];
    }
    __syncthreads();

    // ---------------- phase A: broadcast writes, s = 1..255 ----------------
    {
        const f4 yv = yc4s[t % (UNITS / 4)];        // constant per thread
        f4* out4 = (f4*)out;
        const int per_row = (SEQ - 1) * UNITS / 4;  // 5100
#pragma unroll
        for (int r = 0; r < RPB; ++r) {
            f4* rowp = out4 + (size_t)(R0 + r) * (SEQ * UNITS / 4) + (UNITS / 4);
#pragma unroll
            for (int k = 0; k < 8; ++k) {
                const int j = t + k * TPB;
                if (j < per_row) __builtin_nontemporal_store(yv, rowp + j);
            }
        }
    }

    // ---------------- phase B: y0 for rows R0..R0+3 ----------------
    // lat = x @ W_lat + b_lat : 512 outputs (4 rows x 128 cols)
    if (t < 512) {
        const int row = t >> 7, col = t & 127;
        float acc = bl[col];
        const float* xr = xs + row * IN_DIM;
#pragma unroll 8
        for (int l = 0; l < IN_DIM; ++l) acc = fmaf(xr[l], Wl[l * LATENT + col], acc);
        lat_s[row * LATENT + col] = acc;
    }
    __syncthreads();

    // fw gates on t<320, bw gates on t>=320 (f gate dead: c0=0; relu(c)=c as c>=0)
    {
        const int half = t / G;            // 0 = fw, 1 = bw (wave-uniform: 320 = 5 waves)
        const int tt = t - half * G;       // 0..319
        const int row = tt / UNITS;        // 0..3
        const int u = tt - row * UNITS;    // 0..79
        const float* K   = half ? Kb : Kf;
        const float* bia = half ? bb : bf;
        float ai = 0.f, ac = 0.f, ao = 0.f;
        const float* lr = lat_s + row * LATENT;
#pragma unroll 4
        for (int k = 0; k < LATENT; ++k) {
            const float lv = lr[k];
            ai = fmaf(lv, K[k * G + u], ai);
            ac = fmaf(lv, K[k * G + 160 + u], ac);
            ao = fmaf(lv, K[k * G + 240 + u], ao);
        }
        h_s[row * H2 + half * UNITS + u] =
            sigf(ao + bia[240 + u]) * sigf(ai + bia[u]) * fmaxf(ac + bia[160 + u], 0.f);
    }
    __syncthreads();

    // output LSTM: y0 = gates(h @ K_1 + b_1), write s=0 slice
    if (t < G) {
        const int row = t / UNITS;         // 0..3
        const int u = t - row * UNITS;     // 0..79
        float ai = 0.f, ac = 0.f, ao = 0.f;
        const float* hr = h_s + row * H2;
#pragma unroll 4
        for (int k = 0; k < H2; ++k) {
            const float hv = hr[k];
            ai = fmaf(hv, K1[k * G + u], ai);
            ac = fmaf(hv, K1[k * G + 160 + u], ac);
            ao = fmaf(hv, K1[k * G + 240 + u], ao);
        }
        const float y = sigf(ao + b1[240 + u]) * sigf(ai + b1[u]) * fmaxf(ac + b1[160 + u], 0.f);
        __builtin_nontemporal_store(y, out + (size_t)(R0 + row) * SEQ * UNITS + u);
    }
}

extern "C" void kernel_launch(void* const* d_in, const int* in_sizes, int n_in,
                              void* d_out, int out_size, void* d_ws, size_t ws_size,
                              hipStream_t stream) {
    const float* x   = (const float*)d_in[0];
    // d_in[1] = size (scalar, fixed 256)
    const float* Wl  = (const float*)d_in[2];
    const float* bl  = (const float*)d_in[3];
    const float* Kf  = (const float*)d_in[4];
    const float* bf  = (const float*)d_in[5];
    const float* Kb  = (const float*)d_in[6];
    const float* bb  = (const float*)d_in[7];
    const float* K1  = (const float*)d_in[8];
    const float* b1  = (const float*)d_in[9];
    float* out = (float*)d_out;
    float* yc  = (float*)d_ws;   // 80 floats

    yc_kernel<<<1, 640, 0, stream>>>(Kf, bf, Kb, bb, K1, b1, yc);
    main_kernel<<<NBLK, TPB, 0, stream>>>(x, Wl, bl, Kf, bf, Kb, bb, K1, b1, yc, out);
}